// Round 5
// baseline (1756.786 us; speedup 1.0000x reference)
//
#include <hip/hip_runtime.h>

// Bidirectional LSTM: V=32000, H=1024, S=512. fp32 in/out.
// SINGLE fused persistent kernel, 256 blocks x 256 threads (1 block/CU).
//
// Round-5: REPLICATED exchange (8 replicas) to kill MALL slice hot-spotting.
//  - All 128 sentinel words of a direction previously lived in 8 cache
//    lines; 128 consumer blocks hammered those lines every poll iteration,
//    serializing at the owning MALL slices (the missing ~4000 cy/step).
//  - Producers now store each h word to 8 replica arrays (8 extra relaxed
//    agent-scope stores per pub lane, non-blocking). Consumer block db polls
//    and reads ONLY replica db&7 -> 8x fewer pollers per line, hot lines
//    spread over 8x more MALL slices.
//  - Each replica carries its own embedded tags {tag=t+1 | fp32 h}; the
//    verify-after-load loop is unchanged -> correctness identical to r4.
//  - Everything else = round-4: one barrier/step, parity-double-buffered hs,
//    per-wave stage_c, acc_x split around the poll, self-zero init.

#define HID 1024
#define SEQ 512
#define NREP 8

__device__ __forceinline__ unsigned int f2bf(float f) {
  union { float f; unsigned int i; } v; v.f = f;
  unsigned int u = v.i;
  return (u + 0x7fffu + ((u >> 16) & 1u)) >> 16;  // RNE
}
__device__ __forceinline__ unsigned int pk(float lo, float hi) {
  return f2bf(lo) | (f2bf(hi) << 16);
}
__device__ __forceinline__ float bflo(unsigned int u) {
  union { unsigned int i; float f; } v; v.i = u << 16; return v.f;
}
__device__ __forceinline__ float bfhi(unsigned int u) {
  union { unsigned int i; float f; } v; v.i = u & 0xffff0000u; return v.f;
}
__device__ __forceinline__ float sigm(float x) { return 1.f / (1.f + __expf(-x)); }
__device__ __forceinline__ float ftanh(float x) {
  return 1.f - 2.f / (__expf(2.f * x) + 1.f);   // exact at saturation
}

__global__ __launch_bounds__(256, 1)
void bilstm_kernel(const int* __restrict__ tokens,
                   const float* __restrict__ emb,
                   const float* __restrict__ Wxf, const float* __restrict__ Whf,
                   const float* __restrict__ bxf, const float* __restrict__ bhf,
                   const float* __restrict__ Wxb, const float* __restrict__ Whb,
                   const float* __restrict__ bxb, const float* __restrict__ bhb,
                   unsigned long long* h_ex,   // [NREP][2][2][1024] u64
                   float* __restrict__ out)    // [SEQ][2048] fp32
{
  extern __shared__ unsigned char smem[];      // 64KB: wx bf16-packed
  uint4* wx_lds = (uint4*)smem;                // wx_lds[m*256 + tid]
  __shared__ alignas(16) float hs[2][HID];     // parity double buffer
  __shared__ alignas(16) float xbuf[2][HID];
  __shared__ int tok_s[SEQ];

  const int b   = blockIdx.x;
  const int d   = (b & 7) >> 2;                // dir by XCD half
  const int db  = (b >> 3) * 4 + (b & 3);      // 0..127 within direction
  const int tid = threadIdx.x;
  const int r   = tid >> 3;                    // 0..31: row = unit_l*4+gate
  const int kc  = tid & 7;                     // 8-way k split
  const int wv  = tid >> 6, lane = tid & 63;
  const int gate = r & 3;
  const int unit = db * 8 + (r >> 2);
  const float* Wh  = d ? Whb : Whf;
  const float* Wxp = d ? Wxb : Wxf;

  // replica base for this dir: rep*4 + d*2 (+ parity), each HID u64
  #define HXP(rep, parq) (h_ex + (((size_t)(rep) * 2 + d) * 2 + (parq)) * HID)
  const int crep = db & (NREP - 1);            // replica this block consumes

  // --- init: Wh slice -> registers, Wx slice -> LDS (bf16 pairs) ---
  float w[128];
  {
    const float* wrow = Wh  + ((size_t)gate * HID + unit) * HID + kc * 8;
    const float* xrow = Wxp + ((size_t)gate * HID + unit) * HID + kc * 8;
    #pragma unroll
    for (int m = 0; m < 16; ++m) {
      const float4 q0 = *(const float4*)(wrow + m * 64);
      const float4 q1 = *(const float4*)(wrow + m * 64 + 4);
      w[m*8+0] = q0.x; w[m*8+1] = q0.y; w[m*8+2] = q0.z; w[m*8+3] = q0.w;
      w[m*8+4] = q1.x; w[m*8+5] = q1.y; w[m*8+6] = q1.z; w[m*8+7] = q1.w;
      const float4 p0 = *(const float4*)(xrow + m * 64);
      const float4 p1 = *(const float4*)(xrow + m * 64 + 4);
      uint4 pq;
      pq.x = pk(p0.x, p0.y); pq.y = pk(p0.z, p0.w);
      pq.z = pk(p1.x, p1.y); pq.w = pk(p1.z, p1.w);
      wx_lds[m * 256 + tid] = pq;
    }
  }

  const int brow = gate * HID + unit;
  const float bias = (d ? bxb[brow] : bxf[brow]) + (d ? bhb[brow] : bhf[brow]);

  const bool pub = ((lane & 31) == 0);         // lanes 0,32 of each wave
  const int  ug  = db * 8 + wv * 2 + (lane >> 5);

  // self-zero ALL replicas' exchange words (same lanes that later publish)
  if (pub) {
    #pragma unroll
    for (int rep = 0; rep < NREP; ++rep) {
      __hip_atomic_store(HXP(rep, 0) + ug, 0ull,
                         __ATOMIC_RELAXED, __HIP_MEMORY_SCOPE_AGENT);
      __hip_atomic_store(HXP(rep, 1) + ug, 0ull,
                         __ATOMIC_RELAXED, __HIP_MEMORY_SCOPE_AGENT);
    }
  }

  // tokens -> LDS; x(0) -> xbuf[0]
  tok_s[tid] = tokens[tid];
  tok_s[tid + 256] = tokens[tid + 256];
  {
    const int s0 = d ? (SEQ - 1) : 0;
    *(float4*)(&xbuf[0][tid * 4]) =
        *(const float4*)(emb + (size_t)tokens[s0] * HID + tid * 4);
  }
  __syncthreads();                             // covers wx_lds/xbuf/tok_s

  float c_state = 0.f;                         // on pub lanes only

  for (int t = 0; t < SEQ; ++t) {
    const int par  = t & 1;
    const int s_io = d ? (SEQ - 1 - t) : t;
    const bool pf  = (t + 1 < SEQ);

    // (1) x(t+1) gather into regs (covered by poll + acc_x)
    float4 xf = {0.f, 0.f, 0.f, 0.f};
    if (pf) {
      const int sn = d ? (SEQ - 2 - t) : (t + 1);
      xf = *(const float4*)(emb + (size_t)tok_s[sn] * HID + tid * 4);
    }

    // (2) acc_x part 1 (m=0..7) on xbuf[par] — producer-visibility slack
    float axv[4] = {0.f, 0.f, 0.f, 0.f};
    const float* xb = xbuf[par];
    #pragma unroll
    for (int m = 0; m < 8; ++m) {
      const uint4  wq = wx_lds[m * 256 + tid];
      const float4 a  = *(const float4*)(&xb[kc * 8 + m * 64]);
      const float4 c4 = *(const float4*)(&xb[kc * 8 + m * 64 + 4]);
      axv[m & 3] += bflo(wq.x) * a.x  + bfhi(wq.x) * a.y
                  + bflo(wq.y) * a.z  + bfhi(wq.y) * a.w
                  + bflo(wq.z) * c4.x + bfhi(wq.z) * c4.y
                  + bflo(wq.w) * c4.z + bfhi(wq.w) * c4.w;
    }

    // (3) poll OWN producer group's sentinel in OWN replica, then issue
    //     own 4 data loads (same replica).
    const int base = tid * 4;
    const unsigned long long* hp = HXP(crep, par ^ 1);   // read parity
    unsigned long long u0 = 0, u1 = 0, u2 = 0, u3 = 0;
    if (t > 0) {
      const unsigned int need = (unsigned int)t;
      const unsigned long long* sp = hp + (tid >> 1) * 8;
      unsigned long long s =
          __hip_atomic_load(sp, __ATOMIC_RELAXED, __HIP_MEMORY_SCOPE_AGENT);
      while ((unsigned int)(s >> 32) != need) {
        __builtin_amdgcn_s_sleep(1);
        s = __hip_atomic_load(sp, __ATOMIC_RELAXED, __HIP_MEMORY_SCOPE_AGENT);
      }
      u0 = __hip_atomic_load(hp+base+0, __ATOMIC_RELAXED, __HIP_MEMORY_SCOPE_AGENT);
      u1 = __hip_atomic_load(hp+base+1, __ATOMIC_RELAXED, __HIP_MEMORY_SCOPE_AGENT);
      u2 = __hip_atomic_load(hp+base+2, __ATOMIC_RELAXED, __HIP_MEMORY_SCOPE_AGENT);
      u3 = __hip_atomic_load(hp+base+3, __ATOMIC_RELAXED, __HIP_MEMORY_SCOPE_AGENT);
    }

    // (4) acc_x part 2 (m=8..15) — hides the data-fetch latency
    #pragma unroll
    for (int m = 8; m < 16; ++m) {
      const uint4  wq = wx_lds[m * 256 + tid];
      const float4 a  = *(const float4*)(&xb[kc * 8 + m * 64]);
      const float4 c4 = *(const float4*)(&xb[kc * 8 + m * 64 + 4]);
      axv[m & 3] += bflo(wq.x) * a.x  + bfhi(wq.x) * a.y
                  + bflo(wq.y) * a.z  + bfhi(wq.y) * a.w
                  + bflo(wq.z) * c4.x + bfhi(wq.z) * c4.y
                  + bflo(wq.w) * c4.z + bfhi(wq.w) * c4.w;
    }

    // (5) x(t+1) -> xbuf[par^1]
    if (pf) *(float4*)(&xbuf[par ^ 1][tid * 4]) = xf;

    // (6) verify tags, fill hs[par]
    float* hcur = hs[par];
    if (t == 0) {
      hcur[base+0] = 0.f; hcur[base+1] = 0.f;
      hcur[base+2] = 0.f; hcur[base+3] = 0.f;
    } else {
      const unsigned int need = (unsigned int)t;
      for (;;) {
        const bool o0 = (unsigned int)(u0 >> 32) == need;
        const bool o1 = (unsigned int)(u1 >> 32) == need;
        const bool o2 = (unsigned int)(u2 >> 32) == need;
        const bool o3 = (unsigned int)(u3 >> 32) == need;
        if (o0 & o1 & o2 & o3) break;
        if (!o0) u0 = __hip_atomic_load(hp+base+0, __ATOMIC_RELAXED, __HIP_MEMORY_SCOPE_AGENT);
        if (!o1) u1 = __hip_atomic_load(hp+base+1, __ATOMIC_RELAXED, __HIP_MEMORY_SCOPE_AGENT);
        if (!o2) u2 = __hip_atomic_load(hp+base+2, __ATOMIC_RELAXED, __HIP_MEMORY_SCOPE_AGENT);
        if (!o3) u3 = __hip_atomic_load(hp+base+3, __ATOMIC_RELAXED, __HIP_MEMORY_SCOPE_AGENT);
      }
      hcur[base+0] = __uint_as_float((unsigned int)u0);
      hcur[base+1] = __uint_as_float((unsigned int)u1);
      hcur[base+2] = __uint_as_float((unsigned int)u2);
      hcur[base+3] = __uint_as_float((unsigned int)u3);
    }
    __syncthreads();                           // B1: hs[par] complete

    // (7) stage b: Wh.h partial (4 accumulators)
    float ah[4] = {0.f, 0.f, 0.f, 0.f};
    #pragma unroll
    for (int m = 0; m < 16; ++m) {
      const float4 a  = *(const float4*)(&hcur[kc * 8 + m * 64]);
      const float4 c4 = *(const float4*)(&hcur[kc * 8 + m * 64 + 4]);
      ah[m & 3] += w[m*8+0] * a.x  + w[m*8+1] * a.y
                 + w[m*8+2] * a.z  + w[m*8+3] * a.w
                 + w[m*8+4] * c4.x + w[m*8+5] * c4.y
                 + w[m*8+6] * c4.z + w[m*8+7] * c4.w;
    }
    float acc = ((ah[0] + ah[1]) + (ah[2] + ah[3]))
              + ((axv[0] + axv[1]) + (axv[2] + axv[3]));
    acc += __shfl_xor(acc, 1);
    acc += __shfl_xor(acc, 2);
    acc += __shfl_xor(acc, 4);                 // all 8 kc lanes: row sum

    // (8) per-wave stage c; publish to ALL replicas
    const float gsum = acc + bias;
    const float a = (gate == 3) ? ftanh(gsum) : sigm(gsum);
    const int gb = lane & 32;
    const float ai  = __shfl(a, gb + 0);
    const float af_ = __shfl(a, gb + 8);
    const float ao  = __shfl(a, gb + 16);
    const float ag  = __shfl(a, gb + 24);
    if (pub) {
      c_state = af_ * c_state + ai * ag;
      const float hv = ao * ftanh(c_state);
      const unsigned long long pkd =
          ((unsigned long long)(unsigned int)(t + 1) << 32)
        | (unsigned long long)__float_as_uint(hv);
      #pragma unroll
      for (int rep = 0; rep < NREP; ++rep)
        __hip_atomic_store(HXP(rep, par) + ug, pkd,
                           __ATOMIC_RELAXED, __HIP_MEMORY_SCOPE_AGENT);
      out[(size_t)s_io * 2048 + d * HID + ug] = hv;
    }
    // single barrier per step: hs/xbuf hazards ordered via parity buffers
  }
  #undef HXP
}

// ---------------------------------------------------------------------------
extern "C" void kernel_launch(void* const* d_in, const int* in_sizes, int n_in,
                              void* d_out, int out_size, void* d_ws, size_t ws_size,
                              hipStream_t stream) {
  const int*   tokens = (const int*)d_in[0];
  const float* emb = (const float*)d_in[3];
  const float* Wxf = (const float*)d_in[4];
  const float* Whf = (const float*)d_in[5];
  const float* bxf = (const float*)d_in[6];
  const float* bhf = (const float*)d_in[7];
  const float* Wxb = (const float*)d_in[8];
  const float* Whb = (const float*)d_in[9];
  const float* bxb = (const float*)d_in[10];
  const float* bhb = (const float*)d_in[11];

  unsigned long long* h_ex = (unsigned long long*)d_ws;   // 8*2*2*8KB = 256KB

  hipFuncSetAttribute((const void*)bilstm_kernel,
                      hipFuncAttributeMaxDynamicSharedMemorySize, 65536);

  bilstm_kernel<<<dim3(256), dim3(256), 65536, stream>>>(
      tokens, emb, Wxf, Whf, bxf, bhf, Wxb, Whb, bxb, bhb,
      h_ex, (float*)d_out);
}